// Round 2
// baseline (2498.892 us; speedup 1.0000x reference)
//
#include <hip/hip_runtime.h>
#include <cstdint>
#include <cstddef>

#define N_NODES 16384
#define N_EDGES 65536
#define ETOT    81920
#define B_GR    32

// ---------------- workspace layout (bytes), total ~132 MB ----------------
static constexpr size_t OFF_XL    = 0;                 // 67,108,864
static constexpr size_t OFF_XR    = 67108864ULL;       // 67,108,864 (gat aliases after logits)
static constexpr size_t OFF_LOGIT = 134217728ULL;      // 327,680  [zeroed]
static constexpr size_t OFF_DEG   = 134545408ULL;      // 65,536   [zeroed]
static constexpr size_t OFF_ODEG  = 134610944ULL;      // 65,536   [zeroed]
static constexpr size_t OFF_CURS  = 134676480ULL;      // 65,536   [zeroed]
static constexpr size_t OFF_ROWP  = 134742016ULL;      // 65,792
static constexpr size_t OFF_CSR   = 134807808ULL;      // 327,680
static constexpr size_t OFF_ALPHA = 135135488ULL;      // 327,680
static constexpr size_t OFF_ELOOP = 135463168ULL;      // 2,048
static constexpr size_t OFF_WLOOP = 135465216ULL;      // 4,096
static constexpr size_t OFF_WGEP  = 135469312ULL;      // 2,097,152
static constexpr size_t OFF_YG    = 137566464ULL;      // 65,536
static constexpr size_t OFF_PG    = 137632000ULL;      // 131,072
static constexpr size_t OFF_PDG   = 137763072ULL;      // 131,072
static constexpr size_t OFF_PGAT  = 137894144ULL;      // 131,072
static constexpr size_t OFF_PS    = 138025216ULL;      // 65,536
static constexpr size_t OFF_PE    = 138090752ULL;      // 65,536
static constexpr size_t OFF_PN    = 138156288ULL;      // 131,072
// end = 138,287,360

__device__ __forceinline__ float leaky01(float v){ return v >= 0.f ? v : 0.01f*v; }
__device__ __forceinline__ float leaky02(float v){ return v >= 0.f ? v : 0.2f*v; }

// ---------------- small prep ----------------
__global__ void k_zero(float* __restrict__ p, int n){
  int i = blockIdx.x*blockDim.x + threadIdx.x;
  if (i < n) p[i] = 0.f;
}

__global__ void k_eloop(const float* __restrict__ We, const float* __restrict__ be,
                        float* __restrict__ e_loop) {
  int j = threadIdx.x; // 512
  float v = 0.f;
  if (j < 511) {
    float s = be[j];
    #pragma unroll
    for (int k=0;k<5;k++) s += We[j*5+k];
    v = leaky01(s);
  }
  e_loop[j] = v;
}

__global__ void k_weloop(const float* __restrict__ e_loop, const float* __restrict__ Wge,
                         float* __restrict__ we_loop) {
  int j = blockIdx.x*blockDim.x + threadIdx.x; // 1024
  float s = 0.f;
  for (int k=0;k<511;k++) s += e_loop[k]*Wge[(size_t)j*511+k];
  we_loop[j] = s;
}

__global__ void k_yg(const float* __restrict__ y, const float* __restrict__ Wg,
                     const float* __restrict__ bg, float* __restrict__ yg) {
  int gid = blockIdx.x*blockDim.x + threadIdx.x; // B*512
  int b = gid >> 9, j = gid & 511;
  float s = bg[j];
  #pragma unroll
  for (int k=0;k<5;k++) s += y[b*5+k]*Wg[j*5+k];
  yg[gid] = leaky01(s);
}

__global__ void k_pad_wge(const float* __restrict__ Wge, float* __restrict__ Wge_p) {
  int gid = blockIdx.x*blockDim.x + threadIdx.x; // 1024*512
  int j = gid >> 9, k = gid & 511;
  Wge_p[gid] = (k < 511) ? Wge[(size_t)j*511+k] : 0.f;
}

// ---------------- CSR build (by dst) + degree counts ----------------
__global__ void k_deg(const int* __restrict__ ei, int* __restrict__ deg, int* __restrict__ odeg) {
  int i = blockIdx.x*blockDim.x + threadIdx.x; // ETOT
  int s, d;
  if (i < N_EDGES) { s = ei[i]; d = ei[N_EDGES + i]; }
  else { s = i - N_EDGES; d = s; }
  atomicAdd(&deg[d], 1);
  atomicAdd(&odeg[s], 1);
}

__global__ __launch_bounds__(1024) void k_scan(const int* __restrict__ deg, int* __restrict__ rowptr) {
  __shared__ int sums[1024];
  int t = threadIdx.x;
  int local[16]; int s = 0;
  #pragma unroll
  for (int i=0;i<16;i++){ local[i] = deg[t*16+i]; s += local[i]; }
  sums[t] = s; __syncthreads();
  for (int off=1; off<1024; off<<=1) {
    int v = (t >= off) ? sums[t-off] : 0;
    __syncthreads();
    sums[t] += v;
    __syncthreads();
  }
  int run = (t==0) ? 0 : sums[t-1];
  if (t==0) rowptr[0] = 0;
  #pragma unroll
  for (int i=0;i<16;i++){ run += local[i]; rowptr[t*16+i+1] = run; }
}

__global__ void k_fill_csr(const int* __restrict__ ei, const int* __restrict__ rowptr,
                           int* __restrict__ cursor, int* __restrict__ csr) {
  int i = blockIdx.x*blockDim.x + threadIdx.x; // ETOT
  int d = (i < N_EDGES) ? ei[N_EDGES + i] : (i - N_EDGES);
  int pos = rowptr[d] + atomicAdd(&cursor[d], 1);
  csr[pos] = i;
}

// ---------------- GEMM 1: xl/xr  C[16384,1024] = leaky01(x⊗Wn+bn) @ W^T + bias ----------------
__global__ __launch_bounds__(256) void k_gemm_h(
    const float* __restrict__ x, const float* __restrict__ Wn, const float* __restrict__ bn,
    const float* __restrict__ W, const float* __restrict__ bias,
    float* __restrict__ C) {
  __shared__ float As[16][68];
  __shared__ float Bs[16][68];
  int tid = threadIdx.x;
  int row0 = blockIdx.x*64, col0 = blockIdx.y*64;
  int tx = tid & 15, ty = tid >> 4;
  int lr = tid >> 2, lk = (tid & 3)*4;
  float acc[4][4] = {};
  float xv = x[row0 + lr];
  const float* wp = W + (size_t)(col0+lr)*512 + lk;
  for (int k0 = 0; k0 < 512; k0 += 16) {
    float4 wn = *(const float4*)(Wn + k0 + lk);
    float4 bb = *(const float4*)(bn + k0 + lk);
    float4 bv = *(const float4*)(wp + k0);
    As[lk+0][lr]=leaky01(xv*wn.x+bb.x);
    As[lk+1][lr]=leaky01(xv*wn.y+bb.y);
    As[lk+2][lr]=leaky01(xv*wn.z+bb.z);
    As[lk+3][lr]=leaky01(xv*wn.w+bb.w);
    Bs[lk+0][lr]=bv.x; Bs[lk+1][lr]=bv.y; Bs[lk+2][lr]=bv.z; Bs[lk+3][lr]=bv.w;
    __syncthreads();
    #pragma unroll
    for (int kk=0; kk<16; kk++) {
      float4 a = *(const float4*)&As[kk][ty*4];
      float4 b = *(const float4*)&Bs[kk][tx*4];
      acc[0][0] += a.x*b.x; acc[0][1] += a.x*b.y; acc[0][2] += a.x*b.z; acc[0][3] += a.x*b.w;
      acc[1][0] += a.y*b.x; acc[1][1] += a.y*b.y; acc[1][2] += a.y*b.z; acc[1][3] += a.y*b.w;
      acc[2][0] += a.z*b.x; acc[2][1] += a.z*b.y; acc[2][2] += a.z*b.z; acc[2][3] += a.z*b.w;
      acc[3][0] += a.w*b.x; acc[3][1] += a.w*b.y; acc[3][2] += a.w*b.z; acc[3][3] += a.w*b.w;
    }
    __syncthreads();
  }
  float4 bb = *(const float4*)(bias + col0 + tx*4);
  #pragma unroll
  for (int i=0;i<4;i++) {
    float4 o;
    o.x = acc[i][0]+bb.x; o.y = acc[i][1]+bb.y; o.z = acc[i][2]+bb.z; o.w = acc[i][3]+bb.w;
    *(float4*)(C + (size_t)(row0+ty*4+i)*1024 + col0 + tx*4) = o;
  }
}

// ---------------- GEMM 2: fused we-GEMM + attention logit ----------------
// A[e,k] = leaky01(be[k] + ea[e]·We[k]) for k<511, 0 for k=511, generated on the fly.
// Epilogue: partial logit = sum_cols leaky02(acc + xl[src][c] + xr[dst][c]) * att[c],
// atomicAdd into logit[e] (16 col-blocks contribute per edge).
__global__ __launch_bounds__(256) void k_gemm_we(
    const float* __restrict__ ea, const float* __restrict__ We, const float* __restrict__ be,
    const float* __restrict__ Wge_p, const int* __restrict__ ei,
    const float* __restrict__ xl, const float* __restrict__ xr,
    const float* __restrict__ att, float* __restrict__ logit) {
  __shared__ float As[16][68];
  __shared__ float Bs[16][68];
  int tid = threadIdx.x;
  int row0 = blockIdx.x*64, col0 = blockIdx.y*64;
  int tx = tid & 15, ty = tid >> 4;
  int lr = tid >> 2, lk = (tid & 3)*4;
  float acc[4][4] = {};
  const float* earow = ea + (size_t)(row0+lr)*5;
  float ea0=earow[0], ea1=earow[1], ea2=earow[2], ea3=earow[3], ea4=earow[4];
  const float* wp = Wge_p + (size_t)(col0+lr)*512 + lk;
  for (int k0 = 0; k0 < 512; k0 += 16) {
    #pragma unroll
    for (int j=0;j<4;j++){
      int k = k0 + lk + j;
      float v = 0.f;
      if (k < 511) {
        const float* w = We + k*5;
        float s = be[k] + ea0*w[0] + ea1*w[1] + ea2*w[2] + ea3*w[3] + ea4*w[4];
        v = leaky01(s);
      }
      As[lk+j][lr] = v;
    }
    float4 bv = *(const float4*)(wp + k0);
    Bs[lk+0][lr]=bv.x; Bs[lk+1][lr]=bv.y; Bs[lk+2][lr]=bv.z; Bs[lk+3][lr]=bv.w;
    __syncthreads();
    #pragma unroll
    for (int kk=0; kk<16; kk++) {
      float4 a = *(const float4*)&As[kk][ty*4];
      float4 b = *(const float4*)&Bs[kk][tx*4];
      acc[0][0] += a.x*b.x; acc[0][1] += a.x*b.y; acc[0][2] += a.x*b.z; acc[0][3] += a.x*b.w;
      acc[1][0] += a.y*b.x; acc[1][1] += a.y*b.y; acc[1][2] += a.y*b.z; acc[1][3] += a.y*b.w;
      acc[2][0] += a.z*b.x; acc[2][1] += a.z*b.y; acc[2][2] += a.z*b.z; acc[2][3] += a.z*b.w;
      acc[3][0] += a.w*b.x; acc[3][1] += a.w*b.y; acc[3][2] += a.w*b.z; acc[3][3] += a.w*b.w;
    }
    __syncthreads();
  }
  float4 at = *(const float4*)(att + col0 + tx*4);
  #pragma unroll
  for (int i=0;i<4;i++) {
    int e = row0 + ty*4 + i;
    int s = ei[e], d = ei[N_EDGES + e];
    float4 a = *(const float4*)(xl + (size_t)s*1024 + col0 + tx*4);
    float4 b = *(const float4*)(xr + (size_t)d*1024 + col0 + tx*4);
    float z, p = 0.f;
    z = acc[i][0]+a.x+b.x; z = leaky02(z); p += z*at.x;
    z = acc[i][1]+a.y+b.y; z = leaky02(z); p += z*at.y;
    z = acc[i][2]+a.z+b.z; z = leaky02(z); p += z*at.z;
    z = acc[i][3]+a.w+b.w; z = leaky02(z); p += z*at.w;
    p += __shfl_down(p, 8, 16);
    p += __shfl_down(p, 4, 16);
    p += __shfl_down(p, 2, 16);
    p += __shfl_down(p, 1, 16);
    if (tx == 0) atomicAdd(&logit[e], p);
  }
}

// ---------------- self-loop logits (one wave per node) ----------------
__global__ __launch_bounds__(256) void k_logit_loops(
    const float* __restrict__ xl, const float* __restrict__ xr,
    const float* __restrict__ we_loop, const float* __restrict__ att,
    float* __restrict__ logit) {
  int wid = threadIdx.x >> 6, lane = threadIdx.x & 63;
  int n = blockIdx.x*4 + wid;   // grid 4096 -> n < 16384
  const float4* a4 = (const float4*)(xl + (size_t)n*1024);
  const float4* b4 = (const float4*)(xr + (size_t)n*1024);
  const float4* c4 = (const float4*)we_loop;
  const float4* t4 = (const float4*)att;
  float sum = 0.f;
  #pragma unroll
  for (int it=0; it<4; it++) {
    int j = lane + it*64;
    float4 a = a4[j], b = b4[j], c = c4[j], t = t4[j];
    float z;
    z = leaky02(a.x+b.x+c.x); sum += z*t.x;
    z = leaky02(a.y+b.y+c.y); sum += z*t.y;
    z = leaky02(a.z+b.z+c.z); sum += z*t.z;
    z = leaky02(a.w+b.w+c.w); sum += z*t.w;
  }
  #pragma unroll
  for (int off=32; off; off>>=1) sum += __shfl_down(sum, off);
  if (lane == 0) logit[N_EDGES + n] = sum;
}

// ---------------- softmax over incoming edges ----------------
__global__ void k_softmax(const int* __restrict__ rowptr, const int* __restrict__ csr,
                          const float* __restrict__ logit, float* __restrict__ alpha) {
  int n = blockIdx.x*blockDim.x + threadIdx.x; // N
  int beg = rowptr[n], end = rowptr[n+1];
  float m = -1e30f;
  for (int p=beg;p<end;p++) m = fmaxf(m, logit[csr[p]]);
  float ssum = 0.f;
  for (int p=beg;p<end;p++) ssum += expf(logit[csr[p]] - m);
  float inv = 1.f/(ssum + 1e-16f);
  for (int p=beg;p<end;p++){
    int e = csr[p];
    alpha[e] = expf(logit[e] - m)*inv;
  }
}

// ---------------- GAT aggregation ----------------
__global__ __launch_bounds__(256) void k_gat(
    const int* __restrict__ ei, const int* __restrict__ rowptr, const int* __restrict__ csr,
    const float* __restrict__ alpha, const float* __restrict__ xl,
    const float* __restrict__ bgat, float* __restrict__ gat) {
  int n = blockIdx.x, tid = threadIdx.x;
  const float4* xl4 = (const float4*)xl;
  float4 acc = ((const float4*)bgat)[tid];
  int beg = rowptr[n], end = rowptr[n+1];
  for (int p=beg;p<end;p++){
    int e = csr[p];
    float a = alpha[e];
    int s = (e < N_EDGES) ? ei[e] : (e - N_EDGES);
    float4 v = xl4[(size_t)s*256 + tid];
    acc.x += a*v.x; acc.y += a*v.y; acc.z += a*v.z; acc.w += a*v.w;
  }
  ((float4*)gat)[(size_t)n*256 + tid] = acc;
}

// ---------------- per-graph weighted sums of gat ----------------
__global__ __launch_bounds__(256) void k_nodepool(
    const float* __restrict__ gat, const int* __restrict__ odeg, const int* __restrict__ rowptr,
    float* __restrict__ P_G, float* __restrict__ P_DG, float* __restrict__ P_gat) {
  int b = blockIdx.x, col = blockIdx.y*256 + threadIdx.x;
  float a1=0.f, a2=0.f, a3=0.f;
  for (int i=0;i<512;i++){
    int n = b*512 + i;
    float g = gat[(size_t)n*1024 + col];
    float od = (float)odeg[n];
    float dg = (float)(rowptr[n+1]-rowptr[n]);
    a1 += od*g; a2 += dg*g; a3 += g;
  }
  P_G[b*1024+col]=a1; P_DG[b*1024+col]=a2; P_gat[b*1024+col]=a3;
}

// ---------------- P_S: graph-membership sum of edge_total [B,512] ----------------
__global__ __launch_bounds__(256) void k_Ps(
    const float* __restrict__ ea, const float* __restrict__ We, const float* __restrict__ be,
    const float* __restrict__ e_loop, const float* __restrict__ alpha,
    float* __restrict__ P_S) {
  __shared__ float sea[640];
  __shared__ float sal[128];
  int b = blockIdx.x, tid = threadIdx.x;
  int c1 = tid, c2 = tid + 256;
  bool v2 = (c2 < 511);
  float w1[5], w2[5]={0,0,0,0,0}, b1v, b2v=0.f;
  #pragma unroll
  for (int q=0;q<5;q++) w1[q] = We[c1*5+q];
  b1v = be[c1];
  if (v2) {
    #pragma unroll
    for (int q=0;q<5;q++) w2[q] = We[c2*5+q];
    b2v = be[c2];
  }
  float acc1 = 512.f*e_loop[c1];
  float acc2 = v2 ? 512.f*e_loop[c2] : 0.f;
  for (int ch=0; ch<16; ch++) {
    int r0 = b*2048 + ch*128;
    __syncthreads();
    for (int i=tid;i<640;i+=256) sea[i] = ea[(size_t)r0*5 + i];
    for (int i=tid;i<128;i+=256) sal[i] = alpha[r0+i];
    __syncthreads();
    for (int rr=0; rr<128; rr++) {
      const float* er = &sea[rr*5];
      acc1 += leaky01(b1v + er[0]*w1[0]+er[1]*w1[1]+er[2]*w1[2]+er[3]*w1[3]+er[4]*w1[4]);
      if (v2) acc2 += leaky01(b2v + er[0]*w2[0]+er[1]*w2[1]+er[2]*w2[2]+er[3]*w2[3]+er[4]*w2[4]);
      else    acc2 += sal[rr];
    }
  }
  if (!v2) { // alpha column: add self-loop alphas of this graph
    for (int i=0;i<512;i++) acc2 += alpha[N_EDGES + b*512 + i];
  }
  P_S[b*512+c1] = acc1;
  P_S[b*512+c2] = acc2;
}

// ---------------- pe: contiguous-chunk mean of edge_total [B,512] ----------------
__global__ __launch_bounds__(256) void k_pe(
    const float* __restrict__ ea, const float* __restrict__ We, const float* __restrict__ be,
    const float* __restrict__ alpha, float* __restrict__ pe) {
  __shared__ float sea[640];
  __shared__ float sal[128];
  int b = blockIdx.x, tid = threadIdx.x;
  int c1 = tid, c2 = tid + 256;
  bool v2 = (c2 < 511);
  float w1[5], w2[5]={0,0,0,0,0}, b1v, b2v=0.f;
  #pragma unroll
  for (int q=0;q<5;q++) w1[q] = We[c1*5+q];
  b1v = be[c1];
  if (v2) {
    #pragma unroll
    for (int q=0;q<5;q++) w2[q] = We[c2*5+q];
    b2v = be[c2];
  }
  float acc1 = 0.f, acc2 = 0.f;
  for (int ch=0; ch<20; ch++) {
    int r0 = b*2560 + ch*128;
    __syncthreads();
    for (int i=tid;i<640;i+=256) {
      int r = r0 + i/5;
      sea[i] = (r < N_EDGES) ? ea[(size_t)r*5 + (i%5)] : 1.0f;  // self-loop edge_attr = 1.0
    }
    for (int i=tid;i<128;i+=256) sal[i] = alpha[r0+i];
    __syncthreads();
    for (int rr=0; rr<128; rr++) {
      const float* er = &sea[rr*5];
      acc1 += leaky01(b1v + er[0]*w1[0]+er[1]*w1[1]+er[2]*w1[2]+er[3]*w1[3]+er[4]*w1[4]);
      if (v2) acc2 += leaky01(b2v + er[0]*w2[0]+er[1]*w2[1]+er[2]*w2[2]+er[3]*w2[3]+er[4]*w2[4]);
      else    acc2 += sal[rr];
    }
  }
  const float sc = 1.f/2560.f;
  pe[b*512+c1] = acc1*sc;
  pe[b*512+c2] = acc2*sc;
}

// ---------------- pn via tiny fused GEMMs: [32,1024] output ----------------
__global__ __launch_bounds__(256) void k_pn(
    const float* __restrict__ P_G, const float* __restrict__ P_DG,
    const float* __restrict__ P_S, const float* __restrict__ P_gat,
    const float* __restrict__ Wm, const float* __restrict__ bm,
    const float* __restrict__ Wmi, const float* __restrict__ bmi,
    const float* __restrict__ Wce, const float* __restrict__ bce,
    float* __restrict__ pn) {
  __shared__ float sPg[1024], sPdg[1024], sPs[512];
  int b = blockIdx.x, col0 = blockIdx.y*64;
  int tid = threadIdx.x, w = tid >> 6, lane = tid & 63;
  for (int i=tid;i<1024;i+=256){ sPg[i]=P_G[b*1024+i]; sPdg[i]=P_DG[b*1024+i]; }
  for (int i=tid;i<512;i+=256) sPs[i]=P_S[b*512+i];
  __syncthreads();
  for (int c=0;c<16;c++){
    int j = col0 + w*16 + c;
    const float* wm  = Wm  + (size_t)j*1024;
    const float* wmi = Wmi + (size_t)j*1024;
    const float* wce = Wce + (size_t)j*512;
    float s = 0.f;
    #pragma unroll 4
    for (int i=0;i<16;i++){ int k = lane + i*64; s += sPg[k]*wm[k] + sPdg[k]*wmi[k]; }
    #pragma unroll 4
    for (int i=0;i<8;i++){ int k = lane + i*64; s += sPs[k]*wce[k]; }
    #pragma unroll
    for (int off=32; off; off>>=1) s += __shfl_down(s, off);
    if (lane == 0) {
      pn[b*1024+j] = (s + P_gat[b*1024+j] + 2560.f*(bm[j]+bmi[j]+bce[j])) * (1.f/512.f);
    }
  }
}

// ---------------- final head ----------------
__global__ __launch_bounds__(256) void k_final(
    const float* __restrict__ pn, const float* __restrict__ pe, const float* __restrict__ yg,
    const float* __restrict__ W1, const float* __restrict__ b1,
    const float* __restrict__ W2, const float* __restrict__ b2,
    float* __restrict__ out) {
  __shared__ float pooled[2048];
  __shared__ float red[256];
  int b = blockIdx.x, tid = threadIdx.x;
  for (int i=tid;i<1024;i+=256) pooled[i]      = pn[b*1024+i];
  for (int i=tid;i<512;i+=256)  pooled[1024+i] = pe[b*512+i];
  for (int i=tid;i<512;i+=256)  pooled[1536+i] = yg[b*512+i];
  __syncthreads();
  const float4* w4 = (const float4*)(W1 + (size_t)tid*2048);
  const float4* p4 = (const float4*)pooled;
  float s = b1[tid];
  for (int k=0;k<512;k++){
    float4 w = w4[k]; float4 p = p4[k];
    s += w.x*p.x + w.y*p.y + w.z*p.z + w.w*p.w;
  }
  s = leaky01(s);
  red[tid] = s * W2[tid];
  __syncthreads();
  for (int off=128; off; off>>=1){
    if (tid < off) red[tid] += red[tid+off];
    __syncthreads();
  }
  if (tid == 0){
    float o = red[0] + b2[0];
    out[b] = 1.f/(1.f+expf(-o));
  }
}

// ---------------- launcher ----------------
extern "C" void kernel_launch(void* const* d_in, const int* in_sizes, int n_in,
                              void* d_out, int out_size, void* d_ws, size_t ws_size,
                              hipStream_t stream) {
  const float* x   = (const float*)d_in[0];
  const int*   ei  = (const int*)  d_in[1];
  const float* ea  = (const float*)d_in[2];
  const float* y   = (const float*)d_in[3];
  const float* Wn  = (const float*)d_in[5];
  const float* bn  = (const float*)d_in[6];
  const float* We  = (const float*)d_in[7];
  const float* be  = (const float*)d_in[8];
  const float* Wg  = (const float*)d_in[9];
  const float* bg  = (const float*)d_in[10];
  const float* Wl  = (const float*)d_in[11];
  const float* bl  = (const float*)d_in[12];
  const float* Wr  = (const float*)d_in[13];
  const float* br  = (const float*)d_in[14];
  const float* Wge = (const float*)d_in[15];
  const float* att = (const float*)d_in[16];
  const float* bgat= (const float*)d_in[17];
  const float* Wm  = (const float*)d_in[18];
  const float* bm  = (const float*)d_in[19];
  const float* Wmi = (const float*)d_in[20];
  const float* bmi = (const float*)d_in[21];
  const float* Wce = (const float*)d_in[22];
  const float* bce = (const float*)d_in[23];
  const float* W1  = (const float*)d_in[24];
  const float* b1  = (const float*)d_in[25];
  const float* W2  = (const float*)d_in[26];
  const float* b2  = (const float*)d_in[27];
  float* out = (float*)d_out;

  char* ws = (char*)d_ws;
  float* xl     = (float*)(ws + OFF_XL);
  float* xr     = (float*)(ws + OFF_XR);
  float* gat    = (float*)(ws + OFF_XR);    // alias: xr dead after logits
  float* logit  = (float*)(ws + OFF_LOGIT);
  int*   deg    = (int*)  (ws + OFF_DEG);
  int*   odeg   = (int*)  (ws + OFF_ODEG);
  int*   cursor = (int*)  (ws + OFF_CURS);
  int*   rowptr = (int*)  (ws + OFF_ROWP);
  int*   csr    = (int*)  (ws + OFF_CSR);
  float* alpha  = (float*)(ws + OFF_ALPHA);
  float* e_loop = (float*)(ws + OFF_ELOOP);
  float* we_loop= (float*)(ws + OFF_WLOOP);
  float* Wge_p  = (float*)(ws + OFF_WGEP);
  float* yg     = (float*)(ws + OFF_YG);
  float* P_G    = (float*)(ws + OFF_PG);
  float* P_DG   = (float*)(ws + OFF_PDG);
  float* P_gat  = (float*)(ws + OFF_PGAT);
  float* P_S    = (float*)(ws + OFF_PS);
  float* pe     = (float*)(ws + OFF_PE);
  float* pn     = (float*)(ws + OFF_PN);

  // zero logit+deg+odeg+cursor (contiguous, 131072 words)
  k_zero<<<dim3(512), dim3(256), 0, stream>>>(logit, 131072);

  // small prep
  k_eloop<<<dim3(1), dim3(512), 0, stream>>>(We, be, e_loop);
  k_weloop<<<dim3(4), dim3(256), 0, stream>>>(e_loop, Wge, we_loop);
  k_yg<<<dim3(64), dim3(256), 0, stream>>>(y, Wg, bg, yg);
  k_pad_wge<<<dim3(2048), dim3(256), 0, stream>>>(Wge, Wge_p);

  // CSR by dst + degrees
  k_deg<<<dim3(320), dim3(256), 0, stream>>>(ei, deg, odeg);
  k_scan<<<dim3(1), dim3(1024), 0, stream>>>(deg, rowptr);
  k_fill_csr<<<dim3(320), dim3(256), 0, stream>>>(ei, rowptr, cursor, csr);

  // xl/xr GEMMs (h generated on the fly)
  k_gemm_h<<<dim3(256,16), dim3(256), 0, stream>>>(x, Wn, bn, Wl, bl, xl);
  k_gemm_h<<<dim3(256,16), dim3(256), 0, stream>>>(x, Wn, bn, Wr, br, xr);

  // fused we-GEMM + logits (original edges), then self-loop logits
  k_gemm_we<<<dim3(1024,16), dim3(256), 0, stream>>>(ea, We, be, Wge_p, ei, xl, xr, att, logit);
  k_logit_loops<<<dim3(4096), dim3(256), 0, stream>>>(xl, xr, we_loop, att, logit);

  // softmax + GAT aggregation
  k_softmax<<<dim3(64), dim3(256), 0, stream>>>(rowptr, csr, logit, alpha);
  k_gat<<<dim3(16384), dim3(256), 0, stream>>>(ei, rowptr, csr, alpha, xl, bgat, gat);

  // per-graph reductions (GeneralConv collapsed into per-graph sums)
  k_nodepool<<<dim3(32,4), dim3(256), 0, stream>>>(gat, odeg, rowptr, P_G, P_DG, P_gat);
  k_Ps<<<dim3(32), dim3(256), 0, stream>>>(ea, We, be, e_loop, alpha, P_S);
  k_pe<<<dim3(32), dim3(256), 0, stream>>>(ea, We, be, alpha, pe);
  k_pn<<<dim3(32,16), dim3(256), 0, stream>>>(P_G, P_DG, P_S, P_gat, Wm, bm, Wmi, bmi, Wce, bce, pn);

  // head
  k_final<<<dim3(32), dim3(256), 0, stream>>>(pn, pe, yg, W1, b1, W2, b2, out);
}

// Round 3
// 1265.427 us; speedup vs baseline: 1.9747x; 1.9747x over previous
//
#include <hip/hip_runtime.h>
#include <cstdint>
#include <cstddef>

#define N_NODES 16384
#define N_EDGES 65536
#define ETOT    81920
#define B_GR    32

typedef __attribute__((ext_vector_type(8))) short bf16x8;
typedef __attribute__((ext_vector_type(4))) float f32x4;

// ---------------- workspace layout (bytes), total ~85 MB ----------------
static constexpr size_t OFF_XLBF  = 0;              // 16384*1024*2 = 33,554,432
static constexpr size_t OFF_XRBF  = 33554432ULL;    // 33,554,432 (gat_bf aliases after logits)
static constexpr size_t OFF_HBF   = 67108864ULL;    // 16,777,216
static constexpr size_t OFF_WLBF  = 83886080ULL;    // 1,048,576
static constexpr size_t OFF_WRBF  = 84934656ULL;    // 1,048,576
static constexpr size_t OFF_WGEBF = 85983232ULL;    // 1,048,576
static constexpr size_t OFF_LOGIT = 87031808ULL;    // 327,680  [zeroed]
static constexpr size_t OFF_DEG   = 87359488ULL;    // 65,536   [zeroed]
static constexpr size_t OFF_ODEG  = 87425024ULL;    // 65,536   [zeroed]
static constexpr size_t OFF_CURS  = 87490560ULL;    // 65,536   [zeroed]
static constexpr size_t OFF_ROWP  = 87556096ULL;    // 65,792
static constexpr size_t OFF_CSR   = 87621888ULL;    // 327,680
static constexpr size_t OFF_ALPHA = 87949568ULL;    // 327,680
static constexpr size_t OFF_ELOOP = 88277248ULL;    // 2,048
static constexpr size_t OFF_WLOOP = 88279296ULL;    // 4,096
static constexpr size_t OFF_YG    = 88283392ULL;    // 65,536
static constexpr size_t OFF_PG    = 88348928ULL;    // 131,072
static constexpr size_t OFF_PDG   = 88480000ULL;    // 131,072
static constexpr size_t OFF_PGAT  = 88611072ULL;    // 131,072
static constexpr size_t OFF_PS    = 88742144ULL;    // 65,536
static constexpr size_t OFF_PE    = 88807680ULL;    // 65,536
static constexpr size_t OFF_PN    = 88873216ULL;    // 131,072
// end = 89,004,288

__device__ __forceinline__ float leaky01(float v){ return v >= 0.f ? v : 0.01f*v; }
__device__ __forceinline__ float leaky02(float v){ return v >= 0.f ? v : 0.2f*v; }
__device__ __forceinline__ unsigned short f2bf(float f){
  union { float f; unsigned u; } v; v.f = f;
  unsigned r = v.u + 0x7FFFu + ((v.u >> 16) & 1u);
  return (unsigned short)(r >> 16);
}
__device__ __forceinline__ float bf2f(unsigned short h){
  union { unsigned u; float f; } v; v.u = ((unsigned)h) << 16;
  return v.f;
}

// ---------------- small prep ----------------
__global__ void k_zero(float* __restrict__ p, int n){
  int i = blockIdx.x*blockDim.x + threadIdx.x;
  if (i < n) p[i] = 0.f;
}

// h_bf[n][j] = bf16(leaky01(x[n]*Wn[j]+bn[j])), 8 elems/thread
__global__ void k_prep_hbf(const float* __restrict__ x, const float* __restrict__ Wn,
                           const float* __restrict__ bn, unsigned short* __restrict__ h_bf) {
  int gid = blockIdx.x*blockDim.x + threadIdx.x;   // 1,048,576 threads
  int base = gid*8;
  int n = base >> 9, j = base & 511;
  float xv = x[n];
  float4 w0 = *(const float4*)(Wn + j);
  float4 w1 = *(const float4*)(Wn + j + 4);
  float4 b0 = *(const float4*)(bn + j);
  float4 b1 = *(const float4*)(bn + j + 4);
  unsigned short o[8];
  o[0]=f2bf(leaky01(xv*w0.x+b0.x)); o[1]=f2bf(leaky01(xv*w0.y+b0.y));
  o[2]=f2bf(leaky01(xv*w0.z+b0.z)); o[3]=f2bf(leaky01(xv*w0.w+b0.w));
  o[4]=f2bf(leaky01(xv*w1.x+b1.x)); o[5]=f2bf(leaky01(xv*w1.y+b1.y));
  o[6]=f2bf(leaky01(xv*w1.z+b1.z)); o[7]=f2bf(leaky01(xv*w1.w+b1.w));
  ((uint4*)h_bf)[gid] = *(const uint4*)o;
}

// generic fp32 -> bf16 convert, 4 elems/thread (n4 = n/4)
__global__ void k_cvt(const float* __restrict__ in, unsigned short* __restrict__ out, int n4){
  int i = blockIdx.x*blockDim.x + threadIdx.x;
  if (i >= n4) return;
  float4 v = ((const float4*)in)[i];
  ushort4 o; o.x=f2bf(v.x); o.y=f2bf(v.y); o.z=f2bf(v.z); o.w=f2bf(v.w);
  ((ushort4*)out)[i] = o;
}

// Wge [1024,511] -> bf16 padded [1024,512]
__global__ void k_cvt_wge(const float* __restrict__ Wge, unsigned short* __restrict__ out){
  int gid = blockIdx.x*blockDim.x + threadIdx.x; // 524288
  int j = gid >> 9, k = gid & 511;
  out[gid] = (k < 511) ? f2bf(Wge[(size_t)j*511 + k]) : (unsigned short)0;
}

__global__ void k_eloop(const float* __restrict__ We, const float* __restrict__ be,
                        float* __restrict__ e_loop) {
  int j = threadIdx.x; // 512
  float v = 0.f;
  if (j < 511) {
    float s = be[j];
    #pragma unroll
    for (int k=0;k<5;k++) s += We[j*5+k];
    v = leaky01(s);
  }
  e_loop[j] = v;
}

__global__ void k_weloop(const float* __restrict__ e_loop, const float* __restrict__ Wge,
                         float* __restrict__ we_loop) {
  int j = blockIdx.x*blockDim.x + threadIdx.x; // 1024
  float s = 0.f;
  for (int k=0;k<511;k++) s += e_loop[k]*Wge[(size_t)j*511+k];
  we_loop[j] = s;
}

__global__ void k_yg(const float* __restrict__ y, const float* __restrict__ Wg,
                     const float* __restrict__ bg, float* __restrict__ yg) {
  int gid = blockIdx.x*blockDim.x + threadIdx.x; // B*512
  int b = gid >> 9, j = gid & 511;
  float s = bg[j];
  #pragma unroll
  for (int k=0;k<5;k++) s += y[b*5+k]*Wg[j*5+k];
  yg[gid] = leaky01(s);
}

// ---------------- CSR build (by dst) + degree counts ----------------
__global__ void k_deg(const int* __restrict__ ei, int* __restrict__ deg, int* __restrict__ odeg) {
  int i = blockIdx.x*blockDim.x + threadIdx.x; // ETOT
  int s, d;
  if (i < N_EDGES) { s = ei[i]; d = ei[N_EDGES + i]; }
  else { s = i - N_EDGES; d = s; }
  atomicAdd(&deg[d], 1);
  atomicAdd(&odeg[s], 1);
}

__global__ __launch_bounds__(1024) void k_scan(const int* __restrict__ deg, int* __restrict__ rowptr) {
  __shared__ int sums[1024];
  int t = threadIdx.x;
  int local[16]; int s = 0;
  #pragma unroll
  for (int i=0;i<16;i++){ local[i] = deg[t*16+i]; s += local[i]; }
  sums[t] = s; __syncthreads();
  for (int off=1; off<1024; off<<=1) {
    int v = (t >= off) ? sums[t-off] : 0;
    __syncthreads();
    sums[t] += v;
    __syncthreads();
  }
  int run = (t==0) ? 0 : sums[t-1];
  if (t==0) rowptr[0] = 0;
  #pragma unroll
  for (int i=0;i<16;i++){ run += local[i]; rowptr[t*16+i+1] = run; }
}

__global__ void k_fill_csr(const int* __restrict__ ei, const int* __restrict__ rowptr,
                           int* __restrict__ cursor, int* __restrict__ csr) {
  int i = blockIdx.x*blockDim.x + threadIdx.x; // ETOT
  int d = (i < N_EDGES) ? ei[N_EDGES + i] : (i - N_EDGES);
  int pos = rowptr[d] + atomicAdd(&cursor[d], 1);
  csr[pos] = i;
}

// ---------------- MFMA GEMM 1: C_bf[16384,1024] = h_bf @ W_bf^T + bias ----------------
// 128x128 tile, 4 waves 2x2, each wave 64x64 (4x4 of 16x16x32 MFMA), BK=32.
__global__ __launch_bounds__(256) void k_mfma_h(
    const unsigned short* __restrict__ h_bf, const unsigned short* __restrict__ W_bf,
    const float* __restrict__ bias, unsigned short* __restrict__ C_bf) {
  __shared__ unsigned short As[128*40];
  __shared__ unsigned short Bs[128*40];
  int tid = threadIdx.x;
  int row0 = blockIdx.x*128, col0 = blockIdx.y*128;
  int w = tid >> 6, lane = tid & 63;
  int wm = w >> 1, wn = w & 1;
  int quad = lane >> 4, l16 = lane & 15;
  int sr = tid >> 1, skh = (tid & 1)*16;
  const unsigned short* ap = h_bf + (size_t)(row0+sr)*512 + skh;
  const unsigned short* wp = W_bf + (size_t)(col0+sr)*512 + skh;
  f32x4 acc[4][4];
  #pragma unroll
  for (int i=0;i<4;i++)
    #pragma unroll
    for (int j=0;j<4;j++) acc[i][j] = (f32x4){0.f,0.f,0.f,0.f};

  for (int k0 = 0; k0 < 512; k0 += 32) {
    uint4 a0 = *(const uint4*)(ap + k0);
    uint4 a1 = *(const uint4*)(ap + k0 + 8);
    uint4 b0 = *(const uint4*)(wp + k0);
    uint4 b1 = *(const uint4*)(wp + k0 + 8);
    *(uint4*)&As[sr*40 + skh]     = a0;
    *(uint4*)&As[sr*40 + skh + 8] = a1;
    *(uint4*)&Bs[sr*40 + skh]     = b0;
    *(uint4*)&Bs[sr*40 + skh + 8] = b1;
    __syncthreads();
    bf16x8 af[4], bf[4];
    #pragma unroll
    for (int mi=0;mi<4;mi++)
      af[mi] = *(const bf16x8*)&As[(wm*64 + mi*16 + l16)*40 + quad*8];
    #pragma unroll
    for (int ni=0;ni<4;ni++)
      bf[ni] = *(const bf16x8*)&Bs[(wn*64 + ni*16 + l16)*40 + quad*8];
    #pragma unroll
    for (int mi=0;mi<4;mi++)
      #pragma unroll
      for (int ni=0;ni<4;ni++)
        acc[mi][ni] = __builtin_amdgcn_mfma_f32_16x16x32_bf16(af[mi], bf[ni], acc[mi][ni], 0, 0, 0);
    __syncthreads();
  }
  float bias4[4];
  #pragma unroll
  for (int ni=0;ni<4;ni++) bias4[ni] = bias[col0 + wn*64 + ni*16 + l16];
  #pragma unroll
  for (int mi=0;mi<4;mi++)
    #pragma unroll
    for (int ni=0;ni<4;ni++) {
      int col = col0 + wn*64 + ni*16 + l16;
      #pragma unroll
      for (int r=0;r<4;r++) {
        int row = row0 + wm*64 + mi*16 + quad*4 + r;
        C_bf[(size_t)row*1024 + col] = f2bf(acc[mi][ni][r] + bias4[ni]);
      }
    }
}

// ---------------- MFMA GEMM 2: fused we-GEMM + attention logits ----------------
// A[e,k] = leaky01(be[k] + ea[e]·We[k]) (bf16, on the fly), B = Wge_bf (padded).
// Epilogue: atomicAdd partial logits.
__global__ __launch_bounds__(256) void k_mfma_we(
    const float* __restrict__ ea, const float* __restrict__ We, const float* __restrict__ be,
    const unsigned short* __restrict__ Wge_bf, const int* __restrict__ ei,
    const unsigned short* __restrict__ xl_bf, const unsigned short* __restrict__ xr_bf,
    const float* __restrict__ att, float* __restrict__ logit) {
  __shared__ unsigned short As[128*40];
  __shared__ unsigned short Bs[128*40];
  int tid = threadIdx.x;
  int row0 = blockIdx.x*128, col0 = blockIdx.y*128;
  int w = tid >> 6, lane = tid & 63;
  int wm = w >> 1, wn = w & 1;
  int quad = lane >> 4, l16 = lane & 15;
  // A staging assignment: 4 rows x 4 ks per thread
  int rg = tid >> 3;          // 0..31 -> rows rg*4..+3
  int kg = tid & 7;           // 0..7  -> k kg*4..+3
  // B staging assignment
  int sr = tid >> 1, skh = (tid & 1)*16;
  const unsigned short* wp = Wge_bf + (size_t)(col0+sr)*512 + skh;
  float ear[4][5];
  #pragma unroll
  for (int i=0;i<4;i++) {
    const float* e5 = ea + (size_t)(row0 + rg*4 + i)*5;
    #pragma unroll
    for (int q=0;q<5;q++) ear[i][q] = e5[q];
  }
  f32x4 acc[4][4];
  #pragma unroll
  for (int i=0;i<4;i++)
    #pragma unroll
    for (int j=0;j<4;j++) acc[i][j] = (f32x4){0.f,0.f,0.f,0.f};

  for (int k0 = 0; k0 < 512; k0 += 32) {
    int kk = k0 + kg*4;
    float L[20]; float be4[4];
    if (kk + 4 <= 508) {  // fully in-bounds vector loads (We has 2555 floats, be 511)
      const float4* wf = (const float4*)(We + (size_t)kk*5);
      *(float4*)&L[0]  = wf[0]; *(float4*)&L[4]  = wf[1];
      *(float4*)&L[8]  = wf[2]; *(float4*)&L[12] = wf[3];
      *(float4*)&L[16] = wf[4];
      *(float4*)&be4[0] = *(const float4*)(be + kk);
    } else {
      #pragma unroll
      for (int j=0;j<4;j++) {
        int k = kk + j;
        if (k < 511) {
          #pragma unroll
          for (int q=0;q<5;q++) L[j*5+q] = We[(size_t)k*5+q];
          be4[j] = be[k];
        } else {
          #pragma unroll
          for (int q=0;q<5;q++) L[j*5+q] = 0.f;
          be4[j] = 0.f;
        }
      }
    }
    #pragma unroll
    for (int i=0;i<4;i++) {
      ushort4 o;
      unsigned short ov[4];
      #pragma unroll
      for (int j=0;j<4;j++) {
        int k = kk + j;
        float s = be4[j] + ear[i][0]*L[j*5+0] + ear[i][1]*L[j*5+1]
                         + ear[i][2]*L[j*5+2] + ear[i][3]*L[j*5+3] + ear[i][4]*L[j*5+4];
        ov[j] = (k < 511) ? f2bf(leaky01(s)) : (unsigned short)0;
      }
      o.x=ov[0]; o.y=ov[1]; o.z=ov[2]; o.w=ov[3];
      *(ushort4*)&As[(rg*4+i)*40 + kg*4] = o;
    }
    uint4 b0 = *(const uint4*)(wp + k0);
    uint4 b1 = *(const uint4*)(wp + k0 + 8);
    *(uint4*)&Bs[sr*40 + skh]     = b0;
    *(uint4*)&Bs[sr*40 + skh + 8] = b1;
    __syncthreads();
    bf16x8 af[4], bf[4];
    #pragma unroll
    for (int mi=0;mi<4;mi++)
      af[mi] = *(const bf16x8*)&As[(wm*64 + mi*16 + l16)*40 + quad*8];
    #pragma unroll
    for (int ni=0;ni<4;ni++)
      bf[ni] = *(const bf16x8*)&Bs[(wn*64 + ni*16 + l16)*40 + quad*8];
    #pragma unroll
    for (int mi=0;mi<4;mi++)
      #pragma unroll
      for (int ni=0;ni<4;ni++)
        acc[mi][ni] = __builtin_amdgcn_mfma_f32_16x16x32_bf16(af[mi], bf[ni], acc[mi][ni], 0, 0, 0);
    __syncthreads();
  }
  // epilogue: partial logits
  float att4[4];
  #pragma unroll
  for (int ni=0;ni<4;ni++) att4[ni] = att[col0 + wn*64 + ni*16 + l16];
  #pragma unroll
  for (int mi=0;mi<4;mi++) {
    #pragma unroll
    for (int r=0;r<4;r++) {
      int e = row0 + wm*64 + mi*16 + quad*4 + r;
      int s = ei[e], d = ei[N_EDGES + e];
      const unsigned short* xlr = xl_bf + (size_t)s*1024;
      const unsigned short* xrr = xr_bf + (size_t)d*1024;
      float p = 0.f;
      #pragma unroll
      for (int ni=0;ni<4;ni++) {
        int col = col0 + wn*64 + ni*16 + l16;
        float z = acc[mi][ni][r] + bf2f(xlr[col]) + bf2f(xrr[col]);
        z = leaky02(z);
        p += z*att4[ni];
      }
      p += __shfl_down(p, 8, 16);
      p += __shfl_down(p, 4, 16);
      p += __shfl_down(p, 2, 16);
      p += __shfl_down(p, 1, 16);
      if (l16 == 0) atomicAdd(&logit[e], p);
    }
  }
}

// ---------------- self-loop logits (one wave per node) ----------------
__global__ __launch_bounds__(256) void k_logit_loops(
    const unsigned short* __restrict__ xl_bf, const unsigned short* __restrict__ xr_bf,
    const float* __restrict__ we_loop, const float* __restrict__ att,
    float* __restrict__ logit) {
  int wid = threadIdx.x >> 6, lane = threadIdx.x & 63;
  int n = blockIdx.x*4 + wid;
  const ushort4* a4 = (const ushort4*)(xl_bf + (size_t)n*1024);
  const ushort4* b4 = (const ushort4*)(xr_bf + (size_t)n*1024);
  const float4* c4 = (const float4*)we_loop;
  const float4* t4 = (const float4*)att;
  float sum = 0.f;
  #pragma unroll
  for (int it=0; it<4; it++) {
    int j = lane + it*64;
    ushort4 ah = a4[j], bh = b4[j];
    float4 c = c4[j], t = t4[j];
    float z;
    z = leaky02(bf2f(ah.x)+bf2f(bh.x)+c.x); sum += z*t.x;
    z = leaky02(bf2f(ah.y)+bf2f(bh.y)+c.y); sum += z*t.y;
    z = leaky02(bf2f(ah.z)+bf2f(bh.z)+c.z); sum += z*t.z;
    z = leaky02(bf2f(ah.w)+bf2f(bh.w)+c.w); sum += z*t.w;
  }
  #pragma unroll
  for (int off=32; off; off>>=1) sum += __shfl_down(sum, off);
  if (lane == 0) logit[N_EDGES + n] = sum;
}

// ---------------- softmax over incoming edges ----------------
__global__ void k_softmax(const int* __restrict__ rowptr, const int* __restrict__ csr,
                          const float* __restrict__ logit, float* __restrict__ alpha) {
  int n = blockIdx.x*blockDim.x + threadIdx.x; // N
  int beg = rowptr[n], end = rowptr[n+1];
  float m = -1e30f;
  for (int p=beg;p<end;p++) m = fmaxf(m, logit[csr[p]]);
  float ssum = 0.f;
  for (int p=beg;p<end;p++) ssum += expf(logit[csr[p]] - m);
  float inv = 1.f/(ssum + 1e-16f);
  for (int p=beg;p<end;p++){
    int e = csr[p];
    alpha[e] = expf(logit[e] - m)*inv;
  }
}

// ---------------- GAT aggregation (bf16 xl, bf16 gat out) ----------------
__global__ __launch_bounds__(256) void k_gat(
    const int* __restrict__ ei, const int* __restrict__ rowptr, const int* __restrict__ csr,
    const float* __restrict__ alpha, const unsigned short* __restrict__ xl_bf,
    const float* __restrict__ bgat, unsigned short* __restrict__ gat_bf) {
  int n = blockIdx.x, tid = threadIdx.x;
  float4 acc = ((const float4*)bgat)[tid];
  int beg = rowptr[n], end = rowptr[n+1];
  for (int p=beg;p<end;p++){
    int e = csr[p];
    float a = alpha[e];
    int s = (e < N_EDGES) ? ei[e] : (e - N_EDGES);
    ushort4 v = ((const ushort4*)(xl_bf + (size_t)s*1024))[tid];
    acc.x += a*bf2f(v.x); acc.y += a*bf2f(v.y); acc.z += a*bf2f(v.z); acc.w += a*bf2f(v.w);
  }
  ushort4 o; o.x=f2bf(acc.x); o.y=f2bf(acc.y); o.z=f2bf(acc.z); o.w=f2bf(acc.w);
  ((ushort4*)(gat_bf + (size_t)n*1024))[tid] = o;
}

// ---------------- per-graph weighted sums of gat ----------------
__global__ __launch_bounds__(256) void k_nodepool(
    const unsigned short* __restrict__ gat_bf, const int* __restrict__ odeg, const int* __restrict__ rowptr,
    float* __restrict__ P_G, float* __restrict__ P_DG, float* __restrict__ P_gat) {
  int b = blockIdx.x, col = blockIdx.y*256 + threadIdx.x;
  float a1=0.f, a2=0.f, a3=0.f;
  for (int i=0;i<512;i++){
    int n = b*512 + i;
    float g = bf2f(gat_bf[(size_t)n*1024 + col]);
    float od = (float)odeg[n];
    float dg = (float)(rowptr[n+1]-rowptr[n]);
    a1 += od*g; a2 += dg*g; a3 += g;
  }
  P_G[b*1024+col]=a1; P_DG[b*1024+col]=a2; P_gat[b*1024+col]=a3;
}

// ---------------- P_S: graph-membership sum of edge_total [B,512] ----------------
__global__ __launch_bounds__(256) void k_Ps(
    const float* __restrict__ ea, const float* __restrict__ We, const float* __restrict__ be,
    const float* __restrict__ e_loop, const float* __restrict__ alpha,
    float* __restrict__ P_S) {
  __shared__ float sea[640];
  __shared__ float sal[128];
  int b = blockIdx.x, tid = threadIdx.x;
  int c1 = tid, c2 = tid + 256;
  bool v2 = (c2 < 511);
  float w1[5], w2[5]={0,0,0,0,0}, b1v, b2v=0.f;
  #pragma unroll
  for (int q=0;q<5;q++) w1[q] = We[c1*5+q];
  b1v = be[c1];
  if (v2) {
    #pragma unroll
    for (int q=0;q<5;q++) w2[q] = We[c2*5+q];
    b2v = be[c2];
  }
  float acc1 = 512.f*e_loop[c1];
  float acc2 = v2 ? 512.f*e_loop[c2] : 0.f;
  for (int ch=0; ch<16; ch++) {
    int r0 = b*2048 + ch*128;
    __syncthreads();
    for (int i=tid;i<640;i+=256) sea[i] = ea[(size_t)r0*5 + i];
    for (int i=tid;i<128;i+=256) sal[i] = alpha[r0+i];
    __syncthreads();
    for (int rr=0; rr<128; rr++) {
      const float* er = &sea[rr*5];
      acc1 += leaky01(b1v + er[0]*w1[0]+er[1]*w1[1]+er[2]*w1[2]+er[3]*w1[3]+er[4]*w1[4]);
      if (v2) acc2 += leaky01(b2v + er[0]*w2[0]+er[1]*w2[1]+er[2]*w2[2]+er[3]*w2[3]+er[4]*w2[4]);
      else    acc2 += sal[rr];
    }
  }
  if (!v2) {
    for (int i=0;i<512;i++) acc2 += alpha[N_EDGES + b*512 + i];
  }
  P_S[b*512+c1] = acc1;
  P_S[b*512+c2] = acc2;
}

// ---------------- pe: contiguous-chunk mean of edge_total [B,512] ----------------
__global__ __launch_bounds__(256) void k_pe(
    const float* __restrict__ ea, const float* __restrict__ We, const float* __restrict__ be,
    const float* __restrict__ alpha, float* __restrict__ pe) {
  __shared__ float sea[640];
  __shared__ float sal[128];
  int b = blockIdx.x, tid = threadIdx.x;
  int c1 = tid, c2 = tid + 256;
  bool v2 = (c2 < 511);
  float w1[5], w2[5]={0,0,0,0,0}, b1v, b2v=0.f;
  #pragma unroll
  for (int q=0;q<5;q++) w1[q] = We[c1*5+q];
  b1v = be[c1];
  if (v2) {
    #pragma unroll
    for (int q=0;q<5;q++) w2[q] = We[c2*5+q];
    b2v = be[c2];
  }
  float acc1 = 0.f, acc2 = 0.f;
  for (int ch=0; ch<20; ch++) {
    int r0 = b*2560 + ch*128;
    __syncthreads();
    for (int i=tid;i<640;i+=256) {
      int r = r0 + i/5;
      sea[i] = (r < N_EDGES) ? ea[(size_t)r*5 + (i%5)] : 1.0f;
    }
    for (int i=tid;i<128;i+=256) sal[i] = alpha[r0+i];
    __syncthreads();
    for (int rr=0; rr<128; rr++) {
      const float* er = &sea[rr*5];
      acc1 += leaky01(b1v + er[0]*w1[0]+er[1]*w1[1]+er[2]*w1[2]+er[3]*w1[3]+er[4]*w1[4]);
      if (v2) acc2 += leaky01(b2v + er[0]*w2[0]+er[1]*w2[1]+er[2]*w2[2]+er[3]*w2[3]+er[4]*w2[4]);
      else    acc2 += sal[rr];
    }
  }
  const float sc = 1.f/2560.f;
  pe[b*512+c1] = acc1*sc;
  pe[b*512+c2] = acc2*sc;
}

// ---------------- pn via tiny fused GEMMs: [32,1024] output ----------------
__global__ __launch_bounds__(256) void k_pn(
    const float* __restrict__ P_G, const float* __restrict__ P_DG,
    const float* __restrict__ P_S, const float* __restrict__ P_gat,
    const float* __restrict__ Wm, const float* __restrict__ bm,
    const float* __restrict__ Wmi, const float* __restrict__ bmi,
    const float* __restrict__ Wce, const float* __restrict__ bce,
    float* __restrict__ pn) {
  __shared__ float sPg[1024], sPdg[1024], sPs[512];
  int b = blockIdx.x, col0 = blockIdx.y*64;
  int tid = threadIdx.x, w = tid >> 6, lane = tid & 63;
  for (int i=tid;i<1024;i+=256){ sPg[i]=P_G[b*1024+i]; sPdg[i]=P_DG[b*1024+i]; }
  for (int i=tid;i<512;i+=256) sPs[i]=P_S[b*512+i];
  __syncthreads();
  for (int c=0;c<16;c++){
    int j = col0 + w*16 + c;
    const float* wm  = Wm  + (size_t)j*1024;
    const float* wmi = Wmi + (size_t)j*1024;
    const float* wce = Wce + (size_t)j*512;
    float s = 0.f;
    #pragma unroll 4
    for (int i=0;i<16;i++){ int k = lane + i*64; s += sPg[k]*wm[k] + sPdg[k]*wmi[k]; }
    #pragma unroll 4
    for (int i=0;i<8;i++){ int k = lane + i*64; s += sPs[k]*wce[k]; }
    #pragma unroll
    for (int off=32; off; off>>=1) s += __shfl_down(s, off);
    if (lane == 0) {
      pn[b*1024+j] = (s + P_gat[b*1024+j] + 2560.f*(bm[j]+bmi[j]+bce[j])) * (1.f/512.f);
    }
  }
}

// ---------------- final head ----------------
__global__ __launch_bounds__(256) void k_final(
    const float* __restrict__ pn, const float* __restrict__ pe, const float* __restrict__ yg,
    const float* __restrict__ W1, const float* __restrict__ b1,
    const float* __restrict__ W2, const float* __restrict__ b2,
    float* __restrict__ out) {
  __shared__ float pooled[2048];
  __shared__ float red[256];
  int b = blockIdx.x, tid = threadIdx.x;
  for (int i=tid;i<1024;i+=256) pooled[i]      = pn[b*1024+i];
  for (int i=tid;i<512;i+=256)  pooled[1024+i] = pe[b*512+i];
  for (int i=tid;i<512;i+=256)  pooled[1536+i] = yg[b*512+i];
  __syncthreads();
  const float4* w4 = (const float4*)(W1 + (size_t)tid*2048);
  const float4* p4 = (const float4*)pooled;
  float s = b1[tid];
  for (int k=0;k<512;k++){
    float4 w = w4[k]; float4 p = p4[k];
    s += w.x*p.x + w.y*p.y + w.z*p.z + w.w*p.w;
  }
  s = leaky01(s);
  red[tid] = s * W2[tid];
  __syncthreads();
  for (int off=128; off; off>>=1){
    if (tid < off) red[tid] += red[tid+off];
    __syncthreads();
  }
  if (tid == 0){
    float o = red[0] + b2[0];
    out[b] = 1.f/(1.f+expf(-o));
  }
}

// ---------------- launcher ----------------
extern "C" void kernel_launch(void* const* d_in, const int* in_sizes, int n_in,
                              void* d_out, int out_size, void* d_ws, size_t ws_size,
                              hipStream_t stream) {
  const float* x   = (const float*)d_in[0];
  const int*   ei  = (const int*)  d_in[1];
  const float* ea  = (const float*)d_in[2];
  const float* y   = (const float*)d_in[3];
  const float* Wn  = (const float*)d_in[5];
  const float* bn  = (const float*)d_in[6];
  const float* We  = (const float*)d_in[7];
  const float* be  = (const float*)d_in[8];
  const float* Wg  = (const float*)d_in[9];
  const float* bg  = (const float*)d_in[10];
  const float* Wl  = (const float*)d_in[11];
  const float* bl  = (const float*)d_in[12];
  const float* Wr  = (const float*)d_in[13];
  const float* br  = (const float*)d_in[14];
  const float* Wge = (const float*)d_in[15];
  const float* att = (const float*)d_in[16];
  const float* bgat= (const float*)d_in[17];
  const float* Wm  = (const float*)d_in[18];
  const float* bm  = (const float*)d_in[19];
  const float* Wmi = (const float*)d_in[20];
  const float* bmi = (const float*)d_in[21];
  const float* Wce = (const float*)d_in[22];
  const float* bce = (const float*)d_in[23];
  const float* W1  = (const float*)d_in[24];
  const float* b1  = (const float*)d_in[25];
  const float* W2  = (const float*)d_in[26];
  const float* b2  = (const float*)d_in[27];
  float* out = (float*)d_out;

  char* ws = (char*)d_ws;
  unsigned short* xl_bf  = (unsigned short*)(ws + OFF_XLBF);
  unsigned short* xr_bf  = (unsigned short*)(ws + OFF_XRBF);
  unsigned short* gat_bf = (unsigned short*)(ws + OFF_XRBF);  // alias: xr dead after logits
  unsigned short* h_bf   = (unsigned short*)(ws + OFF_HBF);
  unsigned short* Wl_bf  = (unsigned short*)(ws + OFF_WLBF);
  unsigned short* Wr_bf  = (unsigned short*)(ws + OFF_WRBF);
  unsigned short* Wge_bf = (unsigned short*)(ws + OFF_WGEBF);
  float* logit  = (float*)(ws + OFF_LOGIT);
  int*   deg    = (int*)  (ws + OFF_DEG);
  int*   odeg   = (int*)  (ws + OFF_ODEG);
  int*   cursor = (int*)  (ws + OFF_CURS);
  int*   rowptr = (int*)  (ws + OFF_ROWP);
  int*   csr    = (int*)  (ws + OFF_CSR);
  float* alpha  = (float*)(ws + OFF_ALPHA);
  float* e_loop = (float*)(ws + OFF_ELOOP);
  float* we_loop= (float*)(ws + OFF_WLOOP);
  float* yg     = (float*)(ws + OFF_YG);
  float* P_G    = (float*)(ws + OFF_PG);
  float* P_DG   = (float*)(ws + OFF_PDG);
  float* P_gat  = (float*)(ws + OFF_PGAT);
  float* P_S    = (float*)(ws + OFF_PS);
  float* pe     = (float*)(ws + OFF_PE);
  float* pn     = (float*)(ws + OFF_PN);

  // zero logit+deg+odeg+cursor (contiguous: 327,680+3*65,536 = 524,288 B = 131072 words)
  k_zero<<<dim3(512), dim3(256), 0, stream>>>(logit, 131072);

  // prep: bf16 conversions + small vectors
  k_prep_hbf<<<dim3(4096), dim3(256), 0, stream>>>(x, Wn, bn, h_bf);
  k_cvt<<<dim3(512), dim3(256), 0, stream>>>(Wl, Wl_bf, 131072);
  k_cvt<<<dim3(512), dim3(256), 0, stream>>>(Wr, Wr_bf, 131072);
  k_cvt_wge<<<dim3(2048), dim3(256), 0, stream>>>(Wge, Wge_bf);
  k_eloop<<<dim3(1), dim3(512), 0, stream>>>(We, be, e_loop);
  k_weloop<<<dim3(4), dim3(256), 0, stream>>>(e_loop, Wge, we_loop);
  k_yg<<<dim3(64), dim3(256), 0, stream>>>(y, Wg, bg, yg);

  // CSR by dst + degrees
  k_deg<<<dim3(320), dim3(256), 0, stream>>>(ei, deg, odeg);
  k_scan<<<dim3(1), dim3(1024), 0, stream>>>(deg, rowptr);
  k_fill_csr<<<dim3(320), dim3(256), 0, stream>>>(ei, rowptr, cursor, csr);

  // MFMA GEMMs: xl, xr
  k_mfma_h<<<dim3(128,8), dim3(256), 0, stream>>>(h_bf, Wl_bf, bl, xl_bf);
  k_mfma_h<<<dim3(128,8), dim3(256), 0, stream>>>(h_bf, Wr_bf, br, xr_bf);

  // fused we-GEMM + logits, then self-loop logits
  k_mfma_we<<<dim3(512,8), dim3(256), 0, stream>>>(ea, We, be, Wge_bf, ei, xl_bf, xr_bf, att, logit);
  k_logit_loops<<<dim3(4096), dim3(256), 0, stream>>>(xl_bf, xr_bf, we_loop, att, logit);

  // softmax + GAT aggregation
  k_softmax<<<dim3(64), dim3(256), 0, stream>>>(rowptr, csr, logit, alpha);
  k_gat<<<dim3(16384), dim3(256), 0, stream>>>(ei, rowptr, csr, alpha, xl_bf, bgat, gat_bf);

  // per-graph reductions
  k_nodepool<<<dim3(32,4), dim3(256), 0, stream>>>(gat_bf, odeg, rowptr, P_G, P_DG, P_gat);
  k_Ps<<<dim3(32), dim3(256), 0, stream>>>(ea, We, be, e_loop, alpha, P_S);
  k_pe<<<dim3(32), dim3(256), 0, stream>>>(ea, We, be, alpha, pe);
  k_pn<<<dim3(32,16), dim3(256), 0, stream>>>(P_G, P_DG, P_S, P_gat, Wm, bm, Wmi, bmi, Wce, bce, pn);

  // head
  k_final<<<dim3(32), dim3(256), 0, stream>>>(pn, pe, yg, W1, b1, W2, b2, out);
}

// Round 4
// 660.519 us; speedup vs baseline: 3.7832x; 1.9158x over previous
//
#include <hip/hip_runtime.h>
#include <cstdint>
#include <cstddef>

#define N_NODES 16384
#define N_EDGES 65536
#define ETOT    81920
#define B_GR    32

typedef __attribute__((ext_vector_type(8))) short bf16x8;
typedef __attribute__((ext_vector_type(4))) float f32x4;

// ---------------- workspace layout (bytes), peak ~137.2 MB ----------------
static constexpr size_t OFF_XL    = 0;              // 33,554,432
static constexpr size_t OFF_XR    = 33554432ULL;    // 33,554,432 (gat_bf aliases; safe: block n reads only xr[n] before writing gat[n])
static constexpr size_t OFF_EBF   = 67108864ULL;    // 67,108,864 (written AFTER xl/xr GEMM)
static constexpr size_t OFF_HBF   = 67108864ULL;    // 16,777,216 (alias inside EBF; dead before E written)
static constexpr size_t OFF_WCAT  = 83886080ULL;    // 2,097,152  (alias inside EBF; dead before E written)
static constexpr size_t OFF_WGEP  = 134217728ULL;   // 1,048,576
// ---- zero zone (contiguous, 1,048,576 B = 262,144 floats) ----
static constexpr size_t OFF_LOGIT = 135266304ULL;   // 327,680
static constexpr size_t OFF_DEG   = 135593984ULL;   // 65,536
static constexpr size_t OFF_ODEG  = 135659520ULL;   // 65,536
static constexpr size_t OFF_CURS  = 135725056ULL;   // 65,536
static constexpr size_t OFF_PG    = 135790592ULL;   // 131,072
static constexpr size_t OFF_PDG   = 135921664ULL;   // 131,072
static constexpr size_t OFF_PGAT  = 136052736ULL;   // 131,072
static constexpr size_t OFF_PS    = 136183808ULL;   // 65,536
static constexpr size_t OFF_PE    = 136249344ULL;   // 65,536
// ---- end zero zone ----
static constexpr size_t OFF_ROWP  = 136314880ULL;   // 65,792
static constexpr size_t OFF_CSR   = 136380672ULL;   // 327,680
static constexpr size_t OFF_ALPHA = 136708352ULL;   // 327,680
static constexpr size_t OFF_WLOOP = 137036032ULL;   // 4,096
static constexpr size_t OFF_YG    = 137040128ULL;   // 65,536
static constexpr size_t OFF_PN    = 137105664ULL;   // 131,072
// end = 137,236,736

__device__ __forceinline__ float leaky01(float v){ return v >= 0.f ? v : 0.01f*v; }
__device__ __forceinline__ float leaky02(float v){ return v >= 0.f ? v : 0.2f*v; }
__device__ __forceinline__ unsigned short f2bf(float f){
  union { float f; unsigned u; } v; v.f = f;
  unsigned r = v.u + 0x7FFFu + ((v.u >> 16) & 1u);
  return (unsigned short)(r >> 16);
}
__device__ __forceinline__ float bf2f(unsigned short h){
  union { unsigned u; float f; } v; v.u = ((unsigned)h) << 16;
  return v.f;
}

// ---------------- merged prep: zero zone, h_bf, Wcat, Wge_p, yg, we_loop ----------------
// grid 4420 blocks x 256
__global__ __launch_bounds__(256) void k_prep0(
    const float* __restrict__ x, const float* __restrict__ Wn, const float* __restrict__ bn,
    const float* __restrict__ Wl, const float* __restrict__ Wr,
    const float* __restrict__ Wge, const float* __restrict__ y,
    const float* __restrict__ Wg, const float* __restrict__ bg,
    const float* __restrict__ We, const float* __restrict__ be,
    float* __restrict__ zone, unsigned short* __restrict__ h_bf,
    unsigned short* __restrict__ Wcat, unsigned short* __restrict__ Wge_p,
    float* __restrict__ yg, float* __restrict__ we_loop) {
  __shared__ float e_lds[512];
  int bx = blockIdx.x, tid = threadIdx.x;
  if (bx < 256) {                       // zero 262,144 floats
    ((float4*)zone)[bx*256 + tid] = (float4){0.f,0.f,0.f,0.f};
  } else if (bx < 1280) {               // h_bf, 8 el/thread
    int gid = (bx-256)*256 + tid;
    int base = gid*8;
    int n = base >> 9, j = base & 511;
    float xv = x[n];
    float4 w0 = *(const float4*)(Wn + j);
    float4 w1 = *(const float4*)(Wn + j + 4);
    float4 b0 = *(const float4*)(bn + j);
    float4 b1 = *(const float4*)(bn + j + 4);
    unsigned short o[8];
    o[0]=f2bf(leaky01(xv*w0.x+b0.x)); o[1]=f2bf(leaky01(xv*w0.y+b0.y));
    o[2]=f2bf(leaky01(xv*w0.z+b0.z)); o[3]=f2bf(leaky01(xv*w0.w+b0.w));
    o[4]=f2bf(leaky01(xv*w1.x+b1.x)); o[5]=f2bf(leaky01(xv*w1.y+b1.y));
    o[6]=f2bf(leaky01(xv*w1.z+b1.z)); o[7]=f2bf(leaky01(xv*w1.w+b1.w));
    ((uint4*)h_bf)[gid] = *(const uint4*)o;
  } else if (bx < 2304) {               // Wcat (Wl rows then Wr rows), 4 el/thread
    int i = (bx-1280)*256 + tid;        // < 262,144
    int base = i*4;
    const float* src = (base < 524288) ? (Wl + base) : (Wr + base - 524288);
    float4 v = *(const float4*)src;
    ushort4 o; o.x=f2bf(v.x); o.y=f2bf(v.y); o.z=f2bf(v.z); o.w=f2bf(v.w);
    ((ushort4*)Wcat)[i] = o;
  } else if (bx < 4352) {               // Wge_p scalar, 524,288 el
    int gid = (bx-2304)*256 + tid;
    int j = gid >> 9, k = gid & 511;
    Wge_p[gid] = (k < 511) ? f2bf(Wge[(size_t)j*511 + k]) : (unsigned short)0;
  } else if (bx < 4416) {               // yg, 16384 el
    int gid = (bx-4352)*256 + tid;
    int b = gid >> 9, j = gid & 511;
    float s = bg[j];
    #pragma unroll
    for (int k=0;k<5;k++) s += y[b*5+k]*Wg[j*5+k];
    yg[gid] = leaky01(s);
  } else {                              // we_loop, 4 blocks x 256 cols
    // recompute e_loop into LDS
    for (int c = tid; c < 512; c += 256) {
      float v = 0.f;
      if (c < 511) {
        float s = be[c];
        #pragma unroll
        for (int q=0;q<5;q++) s += We[c*5+q];
        v = leaky01(s);
      }
      e_lds[c] = v;
    }
    __syncthreads();
    int j = (bx-4416)*256 + tid;  // 0..1023
    float s = 0.f;
    for (int k=0;k<511;k++) s += e_lds[k]*Wge[(size_t)j*511+k];
    we_loop[j] = s;
  }
}

// ---------------- E_bf prep: E[e][k] = bf16(leaky01(be+ea·We)), col 511 = 0 ----------------
// grid 16384 x 256; 8 cols/thread
__global__ __launch_bounds__(256) void k_prep_e(
    const float* __restrict__ ea, const float* __restrict__ We, const float* __restrict__ be,
    unsigned short* __restrict__ E_bf) {
  int gid = blockIdx.x*256 + threadIdx.x;   // 4,194,304
  int e = gid >> 6, cg = gid & 63;
  int c0 = cg*8;
  const float* e5 = ea + (size_t)e*5;
  float a0=e5[0], a1=e5[1], a2=e5[2], a3=e5[3], a4=e5[4];
  unsigned short o[8];
  #pragma unroll
  for (int j=0;j<8;j++) {
    int c = c0 + j;
    float v = 0.f;
    if (c < 511) {
      const float* w = We + c*5;
      float s = be[c] + a0*w[0] + a1*w[1] + a2*w[2] + a3*w[3] + a4*w[4];
      v = leaky01(s);
    }
    o[j] = f2bf(v);
  }
  ((uint4*)E_bf)[gid] = *(const uint4*)o;
}

// ---------------- CSR build ----------------
__global__ void k_deg(const int* __restrict__ ei, int* __restrict__ deg, int* __restrict__ odeg) {
  int i = blockIdx.x*blockDim.x + threadIdx.x; // ETOT
  int s, d;
  if (i < N_EDGES) { s = ei[i]; d = ei[N_EDGES + i]; }
  else { s = i - N_EDGES; d = s; }
  atomicAdd(&deg[d], 1);
  atomicAdd(&odeg[s], 1);
}

__global__ __launch_bounds__(1024) void k_scan(const int* __restrict__ deg, int* __restrict__ rowptr) {
  __shared__ int sums[1024];
  int t = threadIdx.x;
  int local[16]; int s = 0;
  #pragma unroll
  for (int i=0;i<16;i++){ local[i] = deg[t*16+i]; s += local[i]; }
  sums[t] = s; __syncthreads();
  for (int off=1; off<1024; off<<=1) {
    int v = (t >= off) ? sums[t-off] : 0;
    __syncthreads();
    sums[t] += v;
    __syncthreads();
  }
  int run = (t==0) ? 0 : sums[t-1];
  if (t==0) rowptr[0] = 0;
  #pragma unroll
  for (int i=0;i<16;i++){ run += local[i]; rowptr[t*16+i+1] = run; }
}

__global__ void k_fill_csr(const int* __restrict__ ei, const int* __restrict__ rowptr,
                           int* __restrict__ cursor, int* __restrict__ csr) {
  int i = blockIdx.x*blockDim.x + threadIdx.x; // ETOT
  int d = (i < N_EDGES) ? ei[N_EDGES + i] : (i - N_EDGES);
  int pos = rowptr[d] + atomicAdd(&cursor[d], 1);
  csr[pos] = i;
}

// ---------------- combined xl/xr MFMA GEMM: [16384,2048] = h_bf @ Wcat^T ----------------
__global__ __launch_bounds__(256) void k_gemm_xlxr(
    const unsigned short* __restrict__ h_bf, const unsigned short* __restrict__ Wcat,
    const float* __restrict__ bl, const float* __restrict__ br,
    unsigned short* __restrict__ xl_bf, unsigned short* __restrict__ xr_bf) {
  __shared__ unsigned short As[128*40];
  __shared__ unsigned short Bs[128*40];
  int tid = threadIdx.x;
  int row0 = blockIdx.x*128, col0 = blockIdx.y*128;
  int w = tid >> 6, lane = tid & 63;
  int wm = w >> 1, wn = w & 1;
  int quad = lane >> 4, l16 = lane & 15;
  int sr = tid >> 1, skh = (tid & 1)*16;
  const unsigned short* ap = h_bf + (size_t)(row0+sr)*512 + skh;
  const unsigned short* wp = Wcat + (size_t)(col0+sr)*512 + skh;
  f32x4 acc[4][4];
  #pragma unroll
  for (int i=0;i<4;i++)
    #pragma unroll
    for (int j=0;j<4;j++) acc[i][j] = (f32x4){0.f,0.f,0.f,0.f};

  for (int k0 = 0; k0 < 512; k0 += 32) {
    uint4 a0 = *(const uint4*)(ap + k0);
    uint4 a1 = *(const uint4*)(ap + k0 + 8);
    uint4 b0 = *(const uint4*)(wp + k0);
    uint4 b1 = *(const uint4*)(wp + k0 + 8);
    *(uint4*)&As[sr*40 + skh]     = a0;
    *(uint4*)&As[sr*40 + skh + 8] = a1;
    *(uint4*)&Bs[sr*40 + skh]     = b0;
    *(uint4*)&Bs[sr*40 + skh + 8] = b1;
    __syncthreads();
    bf16x8 af[4], bfr[4];
    #pragma unroll
    for (int mi=0;mi<4;mi++)
      af[mi] = *(const bf16x8*)&As[(wm*64 + mi*16 + l16)*40 + quad*8];
    #pragma unroll
    for (int ni=0;ni<4;ni++)
      bfr[ni] = *(const bf16x8*)&Bs[(wn*64 + ni*16 + l16)*40 + quad*8];
    #pragma unroll
    for (int mi=0;mi<4;mi++)
      #pragma unroll
      for (int ni=0;ni<4;ni++)
        acc[mi][ni] = __builtin_amdgcn_mfma_f32_16x16x32_bf16(af[mi], bfr[ni], acc[mi][ni], 0, 0, 0);
    __syncthreads();
  }
  bool isL = (blockIdx.y < 8);
  const float* bias = isL ? bl : br;
  unsigned short* O = isL ? xl_bf : xr_bf;
  int cb = isL ? col0 : (col0 - 1024);
  float bias4[4];
  #pragma unroll
  for (int ni=0;ni<4;ni++) bias4[ni] = bias[cb + wn*64 + ni*16 + l16];
  #pragma unroll
  for (int mi=0;mi<4;mi++)
    #pragma unroll
    for (int ni=0;ni<4;ni++) {
      int col = cb + wn*64 + ni*16 + l16;
      #pragma unroll
      for (int r=0;r<4;r++) {
        int row = row0 + wm*64 + mi*16 + quad*4 + r;
        O[(size_t)row*1024 + col] = f2bf(acc[mi][ni][r] + bias4[ni]);
      }
    }
}

// ---------------- we-GEMM + fused attention logits (copy staging from E_bf) ----------------
__global__ __launch_bounds__(256) void k_mfma_we(
    const unsigned short* __restrict__ E_bf, const unsigned short* __restrict__ Wge_bf,
    const int* __restrict__ ei,
    const unsigned short* __restrict__ xl_bf, const unsigned short* __restrict__ xr_bf,
    const float* __restrict__ att, float* __restrict__ logit) {
  __shared__ unsigned short As[128*40];
  __shared__ unsigned short Bs[128*40];
  int tid = threadIdx.x;
  int row0 = blockIdx.x*128, col0 = blockIdx.y*128;
  int w = tid >> 6, lane = tid & 63;
  int wm = w >> 1, wn = w & 1;
  int quad = lane >> 4, l16 = lane & 15;
  int sr = tid >> 1, skh = (tid & 1)*16;
  const unsigned short* ap = E_bf  + (size_t)(row0+sr)*512 + skh;
  const unsigned short* wp = Wge_bf + (size_t)(col0+sr)*512 + skh;
  f32x4 acc[4][4];
  #pragma unroll
  for (int i=0;i<4;i++)
    #pragma unroll
    for (int j=0;j<4;j++) acc[i][j] = (f32x4){0.f,0.f,0.f,0.f};

  for (int k0 = 0; k0 < 512; k0 += 32) {
    uint4 a0 = *(const uint4*)(ap + k0);
    uint4 a1 = *(const uint4*)(ap + k0 + 8);
    uint4 b0 = *(const uint4*)(wp + k0);
    uint4 b1 = *(const uint4*)(wp + k0 + 8);
    *(uint4*)&As[sr*40 + skh]     = a0;
    *(uint4*)&As[sr*40 + skh + 8] = a1;
    *(uint4*)&Bs[sr*40 + skh]     = b0;
    *(uint4*)&Bs[sr*40 + skh + 8] = b1;
    __syncthreads();
    bf16x8 af[4], bfr[4];
    #pragma unroll
    for (int mi=0;mi<4;mi++)
      af[mi] = *(const bf16x8*)&As[(wm*64 + mi*16 + l16)*40 + quad*8];
    #pragma unroll
    for (int ni=0;ni<4;ni++)
      bfr[ni] = *(const bf16x8*)&Bs[(wn*64 + ni*16 + l16)*40 + quad*8];
    #pragma unroll
    for (int mi=0;mi<4;mi++)
      #pragma unroll
      for (int ni=0;ni<4;ni++)
        acc[mi][ni] = __builtin_amdgcn_mfma_f32_16x16x32_bf16(af[mi], bfr[ni], acc[mi][ni], 0, 0, 0);
    __syncthreads();
  }
  float att4[4];
  #pragma unroll
  for (int ni=0;ni<4;ni++) att4[ni] = att[col0 + wn*64 + ni*16 + l16];
  #pragma unroll
  for (int mi=0;mi<4;mi++) {
    #pragma unroll
    for (int r=0;r<4;r++) {
      int e = row0 + wm*64 + mi*16 + quad*4 + r;
      int s = ei[e], d = ei[N_EDGES + e];
      const unsigned short* xlr = xl_bf + (size_t)s*1024;
      const unsigned short* xrr = xr_bf + (size_t)d*1024;
      float p = 0.f;
      #pragma unroll
      for (int ni=0;ni<4;ni++) {
        int col = col0 + wn*64 + ni*16 + l16;
        float z = acc[mi][ni][r] + bf2f(xlr[col]) + bf2f(xrr[col]);
        z = leaky02(z);
        p += z*att4[ni];
      }
      p += __shfl_down(p, 8, 16);
      p += __shfl_down(p, 4, 16);
      p += __shfl_down(p, 2, 16);
      p += __shfl_down(p, 1, 16);
      if (l16 == 0) atomicAdd(&logit[e], p);
    }
  }
}

// ---------------- fused: self-loop logit + softmax + GAT aggregation ----------------
__global__ __launch_bounds__(256) void k_softmax_gat(
    const int* __restrict__ ei, const int* __restrict__ rowptr, const int* __restrict__ csr,
    const float* __restrict__ logit,
    const unsigned short* __restrict__ xl_bf, const unsigned short* __restrict__ xr_bf,
    const float* __restrict__ we_loop, const float* __restrict__ att,
    const float* __restrict__ bgat,
    float* __restrict__ alpha, unsigned short* __restrict__ gat_bf) {
  __shared__ float sl[256];
  __shared__ int   se[256];
  __shared__ float red[256];
  int n = blockIdx.x, tid = threadIdx.x;
  // self-loop logit: dot(leaky02(xl[n]+xr[n]+we_loop), att)
  {
    ushort4 a = ((const ushort4*)(xl_bf + (size_t)n*1024))[tid];
    ushort4 b = ((const ushort4*)(xr_bf + (size_t)n*1024))[tid];
    float4 c = ((const float4*)we_loop)[tid];
    float4 t = ((const float4*)att)[tid];
    float s = 0.f;
    s += leaky02(bf2f(a.x)+bf2f(b.x)+c.x)*t.x;
    s += leaky02(bf2f(a.y)+bf2f(b.y)+c.y)*t.y;
    s += leaky02(bf2f(a.z)+bf2f(b.z)+c.z)*t.z;
    s += leaky02(bf2f(a.w)+bf2f(b.w)+c.w)*t.w;
    red[tid] = s;
  }
  __syncthreads();
  #pragma unroll
  for (int off=128; off; off>>=1){ if (tid<off) red[tid] += red[tid+off]; __syncthreads(); }
  float sll = red[0];
  __syncthreads();

  int beg = rowptr[n], end = rowptr[n+1], cnt = end - beg;
  float m = -1e30f;
  for (int p = beg+tid; p < end; p += 256) {
    int e = csr[p];
    float lg = (e < N_EDGES) ? logit[e] : sll;
    int idx = p - beg;
    if (idx < 256) { se[idx] = e; sl[idx] = lg; }
    m = fmaxf(m, lg);
  }
  red[tid] = m; __syncthreads();
  #pragma unroll
  for (int off=128; off; off>>=1){ if (tid<off) red[tid] = fmaxf(red[tid], red[tid+off]); __syncthreads(); }
  m = red[0];
  __syncthreads();
  float ss = 0.f;
  for (int p = beg+tid; p < end; p += 256) {
    int idx = p - beg;
    float lg;
    if (idx < 256) lg = sl[idx];
    else { int e = csr[p]; lg = (e < N_EDGES) ? logit[e] : sll; }
    ss += expf(lg - m);
  }
  red[tid] = ss; __syncthreads();
  #pragma unroll
  for (int off=128; off; off>>=1){ if (tid<off) red[tid] += red[tid+off]; __syncthreads(); }
  float inv = 1.f/(red[0] + 1e-16f);
  __syncthreads();
  for (int p = beg+tid; p < end; p += 256) {
    int idx = p - beg;
    int e; float lg;
    if (idx < 256) { e = se[idx]; lg = sl[idx]; }
    else { e = csr[p]; lg = (e < N_EDGES) ? logit[e] : sll; }
    float a = expf(lg - m)*inv;
    alpha[e] = a;
    if (idx < 256) sl[idx] = a;
  }
  __syncthreads();
  // aggregation
  float4 acc = ((const float4*)bgat)[tid];
  for (int p = 0; p < cnt; p++) {
    float a; int e;
    if (p < 256) { a = sl[p]; e = se[p]; }
    else { e = csr[beg+p]; float lg = (e < N_EDGES) ? logit[e] : sll; a = expf(lg - m)*inv; }
    int s = (e < N_EDGES) ? ei[e] : (e - N_EDGES);
    ushort4 v = ((const ushort4*)(xl_bf + (size_t)s*1024))[tid];
    acc.x += a*bf2f(v.x); acc.y += a*bf2f(v.y); acc.z += a*bf2f(v.z); acc.w += a*bf2f(v.w);
  }
  ushort4 o; o.x=f2bf(acc.x); o.y=f2bf(acc.y); o.z=f2bf(acc.z); o.w=f2bf(acc.w);
  ((ushort4*)(gat_bf + (size_t)n*1024))[tid] = o;
}

// ---------------- per-graph weighted sums of gat (widened, atomic) ----------------
// grid (32, 16): y>>2 = node chunk (128 nodes), y&3 = col group (256 cols)
__global__ __launch_bounds__(256) void k_nodepool(
    const unsigned short* __restrict__ gat_bf, const int* __restrict__ odeg,
    const int* __restrict__ rowptr,
    float* __restrict__ P_G, float* __restrict__ P_DG, float* __restrict__ P_gat) {
  int b = blockIdx.x, yy = blockIdx.y;
  int nc = yy >> 2, cg = yy & 3;
  int col = cg*256 + threadIdx.x;
  float a1=0.f, a2=0.f, a3=0.f;
  int n0 = b*512 + nc*128;
  for (int i=0;i<128;i++){
    int n = n0 + i;
    float g = bf2f(gat_bf[(size_t)n*1024 + col]);
    float od = (float)odeg[n];
    float dg = (float)(rowptr[n+1]-rowptr[n]);
    a1 += od*g; a2 += dg*g; a3 += g;
  }
  atomicAdd(&P_G[b*1024+col], a1);
  atomicAdd(&P_DG[b*1024+col], a2);
  atomicAdd(&P_gat[b*1024+col], a3);
}

// ---------------- edge pooling (unified P_S / pe), grid (32, 20) ----------------
// mode 0: graph-membership sum -> P_S. chunks 0..15: edges b*2048+ch*128; 16..19: self nodes b*512+(ch-16)*128
// mode 1: contiguous-row mean -> pe. rows b*2560+ch*128 (mixed edges/self handled by rid>=N_EDGES)
__global__ __launch_bounds__(256) void k_edgepool(
    const float* __restrict__ ea, const float* __restrict__ We, const float* __restrict__ be,
    const float* __restrict__ alpha, float* __restrict__ P_S, float* __restrict__ pe, int mode) {
  __shared__ float sea[640];
  __shared__ float sal[128];
  int b = blockIdx.x, ch = blockIdx.y, tid = threadIdx.x;
  int c1 = tid, c2 = tid + 256;
  bool v2 = (c2 < 511);
  float w1[5], w2[5]={0,0,0,0,0}, b1v, b2v=0.f;
  #pragma unroll
  for (int q=0;q<5;q++) w1[q] = We[c1*5+q];
  b1v = be[c1];
  if (v2) {
    #pragma unroll
    for (int q=0;q<5;q++) w2[q] = We[c2*5+q];
    b2v = be[c2];
  }
  int base = (mode == 0)
    ? ((ch < 16) ? (b*2048 + ch*128) : (N_EDGES + b*512 + (ch-16)*128))
    : (b*2560 + ch*128);
  for (int i=tid;i<640;i+=256){
    int r = base + i/5;
    sea[i] = (r < N_EDGES) ? ea[(size_t)r*5 + (i%5)] : 1.0f;
  }
  for (int i=tid;i<128;i+=256) sal[i] = alpha[base + i];
  __syncthreads();
  float acc1 = 0.f, acc2 = 0.f;
  for (int rr=0; rr<128; rr++) {
    const float* er = &sea[rr*5];
    acc1 += leaky01(b1v + er[0]*w1[0]+er[1]*w1[1]+er[2]*w1[2]+er[3]*w1[3]+er[4]*w1[4]);
    if (v2) acc2 += leaky01(b2v + er[0]*w2[0]+er[1]*w2[1]+er[2]*w2[2]+er[3]*w2[3]+er[4]*w2[4]);
    else    acc2 += sal[rr];
  }
  if (mode == 0) {
    atomicAdd(&P_S[b*512+c1], acc1);
    atomicAdd(&P_S[b*512+c2], acc2);
  } else {
    const float sc = 1.f/2560.f;
    atomicAdd(&pe[b*512+c1], acc1*sc);
    atomicAdd(&pe[b*512+c2], acc2*sc);
  }
}

// ---------------- pn via tiny fused GEMMs ----------------
__global__ __launch_bounds__(256) void k_pn(
    const float* __restrict__ P_G, const float* __restrict__ P_DG,
    const float* __restrict__ P_S, const float* __restrict__ P_gat,
    const float* __restrict__ Wm, const float* __restrict__ bm,
    const float* __restrict__ Wmi, const float* __restrict__ bmi,
    const float* __restrict__ Wce, const float* __restrict__ bce,
    float* __restrict__ pn) {
  __shared__ float sPg[1024], sPdg[1024], sPs[512];
  int b = blockIdx.x, col0 = blockIdx.y*64;
  int tid = threadIdx.x, w = tid >> 6, lane = tid & 63;
  for (int i=tid;i<1024;i+=256){ sPg[i]=P_G[b*1024+i]; sPdg[i]=P_DG[b*1024+i]; }
  for (int i=tid;i<512;i+=256) sPs[i]=P_S[b*512+i];
  __syncthreads();
  for (int c=0;c<16;c++){
    int j = col0 + w*16 + c;
    const float* wm  = Wm  + (size_t)j*1024;
    const float* wmi = Wmi + (size_t)j*1024;
    const float* wce = Wce + (size_t)j*512;
    float s = 0.f;
    #pragma unroll 4
    for (int i=0;i<16;i++){ int k = lane + i*64; s += sPg[k]*wm[k] + sPdg[k]*wmi[k]; }
    #pragma unroll 4
    for (int i=0;i<8;i++){ int k = lane + i*64; s += sPs[k]*wce[k]; }
    #pragma unroll
    for (int off=32; off; off>>=1) s += __shfl_down(s, off);
    if (lane == 0) {
      pn[b*1024+j] = (s + P_gat[b*1024+j] + 2560.f*(bm[j]+bmi[j]+bce[j])) * (1.f/512.f);
    }
  }
}

// ---------------- final head ----------------
__global__ __launch_bounds__(256) void k_final(
    const float* __restrict__ pn, const float* __restrict__ pe, const float* __restrict__ yg,
    const float* __restrict__ W1, const float* __restrict__ b1,
    const float* __restrict__ W2, const float* __restrict__ b2,
    float* __restrict__ out) {
  __shared__ float pooled[2048];
  __shared__ float red[256];
  int b = blockIdx.x, tid = threadIdx.x;
  for (int i=tid;i<1024;i+=256) pooled[i]      = pn[b*1024+i];
  for (int i=tid;i<512;i+=256)  pooled[1024+i] = pe[b*512+i];
  for (int i=tid;i<512;i+=256)  pooled[1536+i] = yg[b*512+i];
  __syncthreads();
  const float4* w4 = (const float4*)(W1 + (size_t)tid*2048);
  const float4* p4 = (const float4*)pooled;
  float s = b1[tid];
  for (int k=0;k<512;k++){
    float4 w = w4[k]; float4 p = p4[k];
    s += w.x*p.x + w.y*p.y + w.z*p.z + w.w*p.w;
  }
  s = leaky01(s);
  red[tid] = s * W2[tid];
  __syncthreads();
  for (int off=128; off; off>>=1){
    if (tid < off) red[tid] += red[tid+off];
    __syncthreads();
  }
  if (tid == 0){
    float o = red[0] + b2[0];
    out[b] = 1.f/(1.f+expf(-o));
  }
}

// ---------------- launcher ----------------
extern "C" void kernel_launch(void* const* d_in, const int* in_sizes, int n_in,
                              void* d_out, int out_size, void* d_ws, size_t ws_size,
                              hipStream_t stream) {
  const float* x   = (const float*)d_in[0];
  const int*   ei  = (const int*)  d_in[1];
  const float* ea  = (const float*)d_in[2];
  const float* y   = (const float*)d_in[3];
  const float* Wn  = (const float*)d_in[5];
  const float* bn  = (const float*)d_in[6];
  const float* We  = (const float*)d_in[7];
  const float* be  = (const float*)d_in[8];
  const float* Wg  = (const float*)d_in[9];
  const float* bg  = (const float*)d_in[10];
  const float* Wl  = (const float*)d_in[11];
  const float* bl  = (const float*)d_in[12];
  const float* Wr  = (const float*)d_in[13];
  const float* br  = (const float*)d_in[14];
  const float* Wge = (const float*)d_in[15];
  const float* att = (const float*)d_in[16];
  const float* bgat= (const float*)d_in[17];
  const float* Wm  = (const float*)d_in[18];
  const float* bm  = (const float*)d_in[19];
  const float* Wmi = (const float*)d_in[20];
  const float* bmi = (const float*)d_in[21];
  const float* Wce = (const float*)d_in[22];
  const float* bce = (const float*)d_in[23];
  const float* W1  = (const float*)d_in[24];
  const float* b1  = (const float*)d_in[25];
  const float* W2  = (const float*)d_in[26];
  const float* b2  = (const float*)d_in[27];
  float* out = (float*)d_out;

  char* ws = (char*)d_ws;
  unsigned short* xl_bf  = (unsigned short*)(ws + OFF_XL);
  unsigned short* xr_bf  = (unsigned short*)(ws + OFF_XR);
  unsigned short* gat_bf = (unsigned short*)(ws + OFF_XR);   // alias (see layout note)
  unsigned short* E_bf   = (unsigned short*)(ws + OFF_EBF);
  unsigned short* h_bf   = (unsigned short*)(ws + OFF_HBF);
  unsigned short* Wcat   = (unsigned short*)(ws + OFF_WCAT);
  unsigned short* Wge_p  = (unsigned short*)(ws + OFF_WGEP);
  float* zone   = (float*)(ws + OFF_LOGIT);
  float* logit  = (float*)(ws + OFF_LOGIT);
  int*   deg    = (int*)  (ws + OFF_DEG);
  int*   odeg   = (int*)  (ws + OFF_ODEG);
  int*   cursor = (int*)  (ws + OFF_CURS);
  float* P_G    = (float*)(ws + OFF_PG);
  float* P_DG   = (float*)(ws + OFF_PDG);
  float* P_gat  = (float*)(ws + OFF_PGAT);
  float* P_S    = (float*)(ws + OFF_PS);
  float* pe     = (float*)(ws + OFF_PE);
  int*   rowptr = (int*)  (ws + OFF_ROWP);
  int*   csr    = (int*)  (ws + OFF_CSR);
  float* alpha  = (float*)(ws + OFF_ALPHA);
  float* we_loop= (float*)(ws + OFF_WLOOP);
  float* yg     = (float*)(ws + OFF_YG);
  float* pn     = (float*)(ws + OFF_PN);

  // 1. merged prep (zero zone + h_bf + Wcat + Wge_p + yg + we_loop)
  k_prep0<<<dim3(4420), dim3(256), 0, stream>>>(x, Wn, bn, Wl, Wr, Wge, y, Wg, bg, We, be,
                                                zone, h_bf, Wcat, Wge_p, yg, we_loop);
  // 2-4. CSR by dst + degrees
  k_deg<<<dim3(320), dim3(256), 0, stream>>>(ei, deg, odeg);
  k_scan<<<dim3(1), dim3(1024), 0, stream>>>(deg, rowptr);
  k_fill_csr<<<dim3(320), dim3(256), 0, stream>>>(ei, rowptr, cursor, csr);
  // 5. combined xl/xr GEMM
  k_gemm_xlxr<<<dim3(128,16), dim3(256), 0, stream>>>(h_bf, Wcat, bl, br, xl_bf, xr_bf);
  // 6. E_bf prep (clobbers h_bf/Wcat)
  k_prep_e<<<dim3(16384), dim3(256), 0, stream>>>(ea, We, be, E_bf);
  // 7. we-GEMM + logits
  k_mfma_we<<<dim3(512,8), dim3(256), 0, stream>>>(E_bf, Wge_p, ei, xl_bf, xr_bf, att, logit);
  // 8. fused softmax + GAT (also computes self-loop logits internally)
  k_softmax_gat<<<dim3(16384), dim3(256), 0, stream>>>(ei, rowptr, csr, logit, xl_bf, xr_bf,
                                                       we_loop, att, bgat, alpha, gat_bf);
  // 9-12. pooling
  k_nodepool<<<dim3(32,16), dim3(256), 0, stream>>>(gat_bf, odeg, rowptr, P_G, P_DG, P_gat);
  k_edgepool<<<dim3(32,20), dim3(256), 0, stream>>>(ea, We, be, alpha, P_S, pe, 0);
  k_edgepool<<<dim3(32,20), dim3(256), 0, stream>>>(ea, We, be, alpha, P_S, pe, 1);
  k_pn<<<dim3(32,16), dim3(256), 0, stream>>>(P_G, P_DG, P_S, P_gat, Wm, bm, Wmi, bmi, Wce, bce, pn);
  // 13. head
  k_final<<<dim3(32), dim3(256), 0, stream>>>(pn, pe, yg, W1, b1, W2, b2, out);
}